// Round 13
// baseline (73.083 us; speedup 1.0000x reference)
//
#include <hip/hip_runtime.h>
#include <hip/hip_bf16.h>
#include <math.h>

// Problem: B=8, N=2048, DIN=DOUT=512, adj binary p=0.01
// out = tanh( D^-1/2 (A v I) D^-1/2 (X W) + b )
//
//   K1 scan_wt   : blk[0,64)=W->WT bf16; blk[64,1088)=adj scan (nibble masks,
//                  16 rows/blk). adj COLD each replay (harness fill evicts L3)
//                  -> 134MB/6.3TB/s ~ 22us = HBM floor.
//   K2 gemm_k    : H = X @ W. 64x128 tile, 1024 blocks, dbuf, fp32-A
//                  reg-staged, WT via global_load_lds, panel -> XCD pin. ~12us.
//   K3 aggregate : BLOCK-per-row: 4 waves split the row's edge list into
//                  quarters (~6 gathers each, all in flight -> ~24/row),
//                  LDS partial-sum reduce, 4-wave coalesced finalize.
//                  batch = blk&7 -> XCD pin (h slice L2-resident).
// Ledger (R8-R12): scan 22 (HBM floor), gemm 12, agg 22 -> target 15-17.

#define NROWS 16384
#define NCOLS 2048
#define DF    512
#define CAP   64        // max edges/row (Binom(2048,0.01): mean ~21.5, P(>=64)~0)

typedef __attribute__((ext_vector_type(8))) short bf16x8;
typedef __attribute__((ext_vector_type(4))) float f32x4;
typedef const void __attribute__((address_space(1))) gvoid_t;
typedef void __attribute__((address_space(3))) svoid_t;

// ---------------------------------------------------------------------------
// K1: blocks [0,64) W->WT bf16; blocks [64,1088) adjacency scan, 16 rows each.
// ---------------------------------------------------------------------------
__global__ __launch_bounds__(256) void scan_wt(
    const float* __restrict__ W, __hip_bfloat16* __restrict__ WT,
    const float* __restrict__ adj, int* __restrict__ cnt,
    int* __restrict__ edges, float* __restrict__ dinv) {
  __shared__ float t[64][65];
  const int blk = blockIdx.x;
  const int tid = threadIdx.x;
  if (blk < 64) {                                  // W -> W^T bf16
    const int bx = blk & 7, by = blk >> 3;
    const int tx = tid & 63, ty = tid >> 6;
    #pragma unroll
    for (int i = 0; i < 16; ++i)
      t[ty + i * 4][tx] = W[(size_t)(by * 64 + ty + i * 4) * DF + bx * 64 + tx];
    __syncthreads();
    #pragma unroll
    for (int i = 0; i < 16; ++i)                   // WT[n][k] = W[k][n]
      WT[(size_t)(bx * 64 + ty + i * 4) * DF + by * 64 + tx] =
          __float2bfloat16(t[tx][ty + i * 4]);
    return;
  }
  // adjacency scan: 16 rows per block, 4 rows per wave, 2-deep pipeline
  const int lane = tid & 63;
  const int wv = tid >> 6;
  const int rbase = (blk - 64) * 16 + wv * 4;
  float4 cur[8], nxt[8];
  {
    const float4* r4 = (const float4*)(adj + (size_t)rbase * NCOLS);
    #pragma unroll
    for (int k = 0; k < 8; ++k) cur[k] = r4[k * 64 + lane];
  }
  #pragma unroll
  for (int g = 0; g < 4; ++g) {
    const int r = rbase + g;
    if (g < 3) {
      const float4* rn = (const float4*)(adj + (size_t)(r + 1) * NCOLS);
      #pragma unroll
      for (int k = 0; k < 8; ++k) nxt[k] = rn[k * 64 + lane];
    }
    const int n = r & (NCOLS - 1);
    unsigned m = 0;
    #pragma unroll
    for (int k = 0; k < 8; ++k) {
      m |= (cur[k].x != 0.0f ? 1u : 0u) << (4 * k);
      m |= (cur[k].y != 0.0f ? 1u : 0u) << (4 * k + 1);
      m |= (cur[k].z != 0.0f ? 1u : 0u) << (4 * k + 2);
      m |= (cur[k].w != 0.0f ? 1u : 0u) << (4 * k + 3);
    }
    if (lane == ((n >> 2) & 63))                   // force self-loop bit
      m |= 1u << (((n >> 8) << 2) | (n & 3));
    const int c_ = __popc(m);
    int inc = c_;                                  // inclusive wave prefix-scan
    #pragma unroll
    for (int off = 1; off < 64; off <<= 1) {
      const int tv = __shfl_up(inc, off);
      if (lane >= off) inc += tv;
    }
    const int tot = __shfl(inc, 63);
    int p = inc - c_;                              // exclusive prefix
    unsigned mm = m;
    const size_t eb = (size_t)r * CAP;
    while (mm) {                                   // <= ~3 iters per lane
      const int bpos = __ffs(mm) - 1;
      mm &= mm - 1;
      if (p < CAP)
        edges[eb + p] = ((bpos >> 2) << 8) + (lane << 2) + (bpos & 3);
      ++p;
    }
    if (lane == 63) {
      cnt[r] = tot < CAP ? tot : CAP;
      dinv[r] = rsqrtf((float)tot);                // deg >= 1 (self-loop)
    }
    #pragma unroll
    for (int k = 0; k < 8; ++k) cur[k] = nxt[k];
  }
}

// ---------------------------------------------------------------------------
// K2: H = X @ WT^T. 64x128 tile, BK=32, 1024 blocks (4+ blocks/CU),
//     4 waves (2x2: 32x64 each), double-buffered LDS (24KB total).
//     A: fp32 reg-staged -> bf16 -> ds_write. B: WT bf16 via global_load_lds.
// ---------------------------------------------------------------------------
__global__ __launch_bounds__(256) void gemm_k(
    const float* __restrict__ X, const __hip_bfloat16* __restrict__ WT,
    __hip_bfloat16* __restrict__ H) {
  __shared__ __hip_bfloat16 As[2][64 * 32];        // 2 x 4 KB  [row][k]
  __shared__ __hip_bfloat16 Bs[2][128 * 32];       // 2 x 8 KB  [n][k]
  const int tid = threadIdx.x;
  const int lane = tid & 63;
  const int w = tid >> 6;
  const int id = blockIdx.x;
  const int xcd = id & 7;
  const int q = id >> 3;                           // 0..127
  const int bm = (xcd * 32 + (q >> 2)) * 64;       // panel -> XCD pin
  const int bn = (q & 3) * 128;

  const int wm = (w >> 1) * 32;                    // wave tile 32x64
  const int wn = (w & 1) * 64;
  const int srow = tid >> 2;                       // staging row (0..63)
  const int scol = (tid & 3) * 8;                  // 8 elems = 16B
  const int kl = (lane >> 4) * 8;
  const int rl = lane & 15;

  f32x4 acc[2][4] = {};
  float4 ar0, ar1;                                 // A prefetch regs (8 floats)

  #define LOAD_A(k0)  do {                                              \
    const float4* g_ = (const float4*)(X + (size_t)(bm + srow) * DF + (k0) + scol); \
    ar0 = g_[0]; ar1 = g_[1]; } while (0)

  #define STAGE_B(k0, buf)  do {                                        \
    _Pragma("unroll")                                                   \
    for (int i = 0; i < 2; ++i) {                                       \
      const __hip_bfloat16* gb = WT + (size_t)(bn + i * 64 + srow) * DF + (k0) + scol; \
      char* lb = (char*)&Bs[buf][0] + i * 4096 + w * 1024;              \
      __builtin_amdgcn_global_load_lds((gvoid_t*)gb, (svoid_t*)lb, 16, 0, 0); \
    } } while (0)

  #define WRITE_A(buf)  do {                                            \
    float xs[8];                                                        \
    *(float4*)&xs[0] = ar0; *(float4*)&xs[4] = ar1;                     \
    union { __hip_bfloat16 hh[8]; uint4 q_; } pk;                       \
    _Pragma("unroll")                                                   \
    for (int i = 0; i < 8; ++i) pk.hh[i] = __float2bfloat16(xs[i]);     \
    char* la = (char*)&As[buf][0] + srow * 64 + scol * 2;               \
    *(uint4*)la = pk.q_; } while (0)

  LOAD_A(0);
  STAGE_B(0, 0);
  WRITE_A(0);
  __syncthreads();

  for (int t = 0; t < 16; ++t) {
    const int c_ = t & 1, nx = c_ ^ 1;
    if (t < 15) {
      LOAD_A((t + 1) * 32);                        // issue next-tile loads first
      STAGE_B((t + 1) * 32, nx);
    }
    bf16x8 af[2], bf[4];
    #pragma unroll
    for (int mi = 0; mi < 2; ++mi)
      af[mi] = *(const bf16x8*)&As[c_][(wm + mi * 16 + rl) * 32 + kl];
    #pragma unroll
    for (int ni = 0; ni < 4; ++ni)
      bf[ni] = *(const bf16x8*)&Bs[c_][(wn + ni * 16 + rl) * 32 + kl];
    #pragma unroll
    for (int mi = 0; mi < 2; ++mi)
      #pragma unroll
      for (int ni = 0; ni < 4; ++ni)
        acc[mi][ni] = __builtin_amdgcn_mfma_f32_16x16x32_bf16(af[mi], bf[ni], acc[mi][ni], 0, 0, 0);
    if (t < 15) WRITE_A(nx);                       // convert+ds_write after MFMA
    __syncthreads();
  }

  const int rq = (lane >> 4) * 4;                  // D: col=lane&15, row=rq+j
  #pragma unroll
  for (int mi = 0; mi < 2; ++mi)
    #pragma unroll
    for (int ni = 0; ni < 4; ++ni) {
      const int col = bn + wn + ni * 16 + rl;
      #pragma unroll
      for (int j = 0; j < 4; ++j) {
        const int row = bm + wm + mi * 16 + rq + j;
        H[(size_t)row * DF + col] = __float2bfloat16(acc[mi][ni][j]);
      }
    }
  #undef LOAD_A
  #undef STAGE_B
  #undef WRITE_A
}

// ---------------------------------------------------------------------------
// fast tanh: 1 - 2/(e^{2x}+1). v_exp + fast-div; saturates correctly at +-inf.
// ---------------------------------------------------------------------------
__device__ __forceinline__ float fast_tanh(float x) {
  const float t = __expf(2.0f * x);
  return 1.0f - __fdividef(2.0f, t + 1.0f);
}

// ---------------------------------------------------------------------------
// K3: aggregate, BLOCK-per-row. 16384 blocks; batch = blk&7 -> XCD pin.
// 4 waves split the edge list into quarters (~6 gathers each, all in flight);
// LDS partial reduce (stride-9 pad -> 2-way banks = free); finalize split
// across 4 waves with coalesced float2 stores.
// ---------------------------------------------------------------------------
__global__ __launch_bounds__(256) void aggregate(
    const __hip_bfloat16* __restrict__ h, const int* __restrict__ cnt,
    const int* __restrict__ edges, const float* __restrict__ dinv,
    const float* __restrict__ bias, float* __restrict__ out) {
  __shared__ float red[4][64][9];
  const int lane = threadIdx.x & 63;
  const int wv = threadIdx.x >> 6;
  const int batch = blockIdx.x & 7;                // -> XCD pin
  const int rn = blockIdx.x >> 3;                  // 0..2047 row within batch
  const int r = (batch << 11) + rn;
  const int c = cnt[r];
  const float* dv = dinv + (batch << 11);
  const uint4* hbase = (const uint4*)(h + (size_t)(batch << 11) * DF);
  const int* eb = edges + (size_t)r * CAP;

  // wave wv owns edges [e0, e1): balanced quarters of the row's list
  const int quarter = (c + 3) >> 2;
  const int e0 = wv * quarter;
  const int e1 = min(e0 + quarter, c);

  float acc[8] = {0.f,0.f,0.f,0.f,0.f,0.f,0.f,0.f};
  for (int e = e0; e < e1; e += 8) {               // usually a single chunk
    int   mj[8];
    float wj[8];
    uint4 vj[8];
    #pragma unroll
    for (int j = 0; j < 8; ++j)                    // broadcast index loads
      if (e + j < e1) mj[j] = eb[e + j];
    #pragma unroll
    for (int j = 0; j < 8; ++j)                    // weights + gathers in flight
      if (e + j < e1) {
        wj[j] = dv[mj[j]];
        vj[j] = hbase[(size_t)mj[j] * 64 + lane];
      }
    #pragma unroll
    for (int j = 0; j < 8; ++j)
      if (e + j < e1) {
        const float wt = wj[j];
        acc[0] += wt * __uint_as_float(vj[j].x << 16);
        acc[1] += wt * __uint_as_float(vj[j].x & 0xffff0000u);
        acc[2] += wt * __uint_as_float(vj[j].y << 16);
        acc[3] += wt * __uint_as_float(vj[j].y & 0xffff0000u);
        acc[4] += wt * __uint_as_float(vj[j].z << 16);
        acc[5] += wt * __uint_as_float(vj[j].z & 0xffff0000u);
        acc[6] += wt * __uint_as_float(vj[j].w << 16);
        acc[7] += wt * __uint_as_float(vj[j].w & 0xffff0000u);
      }
  }
  #pragma unroll
  for (int j = 0; j < 8; ++j) red[wv][lane][j] = acc[j];
  __syncthreads();

  // finalize: wave wv handles feats [wv*128, wv*128+128); lane does 2 feats
  const int f = wv * 128 + lane * 2;               // even; f&7 in {0,2,4,6}
  const int l2 = f >> 3;                           // source lane of this feat
  const int j2 = f & 7;
  const float s0 = red[0][l2][j2]     + red[1][l2][j2]
                 + red[2][l2][j2]     + red[3][l2][j2];
  const float s1 = red[0][l2][j2 + 1] + red[1][l2][j2 + 1]
                 + red[2][l2][j2 + 1] + red[3][l2][j2 + 1];
  const float dn = dv[rn];
  float2 o;
  o.x = fast_tanh(s0 * dn + bias[f]);
  o.y = fast_tanh(s1 * dn + bias[f + 1]);
  *(float2*)(out + (size_t)r * DF + f) = o;        // coalesced 512B per wave
}

// ---------------------------------------------------------------------------
extern "C" void kernel_launch(void* const* d_in, const int* in_sizes, int n_in,
                              void* d_out, int out_size, void* d_ws, size_t ws_size,
                              hipStream_t stream) {
  const float* X    = (const float*)d_in[0];   // [8,2048,512]
  const float* adj  = (const float*)d_in[1];   // [8,2048,2048]
  const float* W    = (const float*)d_in[2];   // [512,512]
  const float* bias = (const float*)d_in[3];   // [512]
  float* out = (float*)d_out;

  char* ws = (char*)d_ws;
  __hip_bfloat16* h    = (__hip_bfloat16*)(ws);                    // 16,777,216 B
  __hip_bfloat16* WT   = (__hip_bfloat16*)(ws + 16777216);         //    524,288 B
  float*          dinv = (float*)(ws + 17301504);                  //     65,536 B
  int*            cnt  = (int*)  (ws + 17367040);                  //     65,536 B
  int*            edges= (int*)  (ws + 17432576);                  //  4,194,304 B
  // total ws: 21,626,880 B

  scan_wt<<<1088, 256, 0, stream>>>(W, WT, adj, cnt, edges, dinv);
  gemm_k<<<1024, 256, 0, stream>>>(X, WT, h);
  aggregate<<<NROWS, 256, 0, stream>>>(h, cnt, edges, dinv, bias, out);
}

// Round 14
// 72.248 us; speedup vs baseline: 1.0116x; 1.0116x over previous
//
#include <hip/hip_runtime.h>
#include <hip/hip_bf16.h>
#include <math.h>

// Problem: B=8, N=2048, DIN=DOUT=512, adj binary p=0.01
// out = tanh( D^-1/2 (A v I) D^-1/2 (X W) + b )
//
//   K0 wt_kernel : W (fp32) -> WT bf16 (WT[n][k]=W[k][n]), 64 blocks, ~2us
//   K1 fused_k   : blocks [0,1024)    = gemm H = X @ W (R12-exact: 64x128,
//                  BK=32, dbuf 24KB, fp32-A reg-staged, WT via DMA, XCD pin)
//                  blocks [1024,2048) = adj scan, 16 rows/blk, SAME-REG
//                  reload pipeline (cur[8] only -> ~50 VGPR; R11's 88-VGPR
//                  nxt[8] spill/serialization was the fusion killer).
//                  Fused floor: 188MB HBM / 6.3TB/s ~ 30us; gemm hides under.
//   K2 aggregate : R12/R9 form (measured floor ~22us = per-XCD L2 gather BW).
// Ledger: scan 22 (HBM floor), gemm 12, agg 22 (L2 floor), gaps ~14.

#define NROWS 16384
#define NCOLS 2048
#define DF    512
#define CAP   64        // max edges/row (Binom(2048,0.01): mean ~21.5, P(>=64)~0)

typedef __attribute__((ext_vector_type(8))) short bf16x8;
typedef __attribute__((ext_vector_type(4))) float f32x4;
typedef const void __attribute__((address_space(1))) gvoid_t;
typedef void __attribute__((address_space(3))) svoid_t;

// ---------------------------------------------------------------------------
// K0: W -> W^T in bf16 (64 blocks of 64x64 tiles)
// ---------------------------------------------------------------------------
__global__ __launch_bounds__(256) void wt_kernel(
    const float* __restrict__ W, __hip_bfloat16* __restrict__ WT) {
  __shared__ float t[64][65];
  const int b2 = blockIdx.x;
  const int bx = b2 & 7, by = b2 >> 3;
  const int tid = threadIdx.x;
  const int tx = tid & 63, ty = tid >> 6;
  #pragma unroll
  for (int i = 0; i < 16; ++i)
    t[ty + i * 4][tx] = W[(size_t)(by * 64 + ty + i * 4) * DF + bx * 64 + tx];
  __syncthreads();
  #pragma unroll
  for (int i = 0; i < 16; ++i)                     // WT[n][k] = W[k][n]
    WT[(size_t)(bx * 64 + ty + i * 4) * DF + by * 64 + tx] =
        __float2bfloat16(t[tx][ty + i * 4]);
}

// ---------------------------------------------------------------------------
// K1: heterogeneous. blocks [0,1024): gemm (R12 structure).
//     blocks [1024,2048): adjacency scan, 16 rows/blk, same-reg pipeline.
// ---------------------------------------------------------------------------
__global__ __launch_bounds__(256) void fused_k(
    const float* __restrict__ X, const __hip_bfloat16* __restrict__ WT,
    const float* __restrict__ adj, __hip_bfloat16* __restrict__ H,
    int* __restrict__ cnt, int* __restrict__ edges, float* __restrict__ dinv) {
  __shared__ __hip_bfloat16 As[2][64 * 32];        // 2 x 4 KB  [row][k]
  __shared__ __hip_bfloat16 Bs[2][128 * 32];       // 2 x 8 KB  [n][k]
  const int id = blockIdx.x;
  const int tid = threadIdx.x;
  const int lane = tid & 63;
  const int wv = tid >> 6;

  if (id < 1024) {
    // ---- GEMM path (R12-exact) ----
    const int xcd = id & 7;
    const int q = id >> 3;                         // 0..127
    const int bm = (xcd * 32 + (q >> 2)) * 64;     // panel -> XCD pin
    const int bn = (q & 3) * 128;
    const int w = wv;
    const int wm = (w >> 1) * 32;                  // wave tile 32x64
    const int wn = (w & 1) * 64;
    const int srow = tid >> 2;                     // staging row (0..63)
    const int scol = (tid & 3) * 8;                // 8 elems = 16B
    const int kl = (lane >> 4) * 8;
    const int rl = lane & 15;

    f32x4 acc[2][4] = {};
    float4 ar0, ar1;                               // A prefetch regs (8 floats)

    #define LOAD_A(k0)  do {                                              \
      const float4* g_ = (const float4*)(X + (size_t)(bm + srow) * DF + (k0) + scol); \
      ar0 = g_[0]; ar1 = g_[1]; } while (0)

    #define STAGE_B(k0, buf)  do {                                        \
      _Pragma("unroll")                                                   \
      for (int i = 0; i < 2; ++i) {                                       \
        const __hip_bfloat16* gb = WT + (size_t)(bn + i * 64 + srow) * DF + (k0) + scol; \
        char* lb = (char*)&Bs[buf][0] + i * 4096 + w * 1024;              \
        __builtin_amdgcn_global_load_lds((gvoid_t*)gb, (svoid_t*)lb, 16, 0, 0); \
      } } while (0)

    #define WRITE_A(buf)  do {                                            \
      float xs[8];                                                        \
      *(float4*)&xs[0] = ar0; *(float4*)&xs[4] = ar1;                     \
      union { __hip_bfloat16 hh[8]; uint4 q_; } pk;                       \
      _Pragma("unroll")                                                   \
      for (int i = 0; i < 8; ++i) pk.hh[i] = __float2bfloat16(xs[i]);     \
      char* la = (char*)&As[buf][0] + srow * 64 + scol * 2;               \
      *(uint4*)la = pk.q_; } while (0)

    LOAD_A(0);
    STAGE_B(0, 0);
    WRITE_A(0);
    __syncthreads();

    for (int t = 0; t < 16; ++t) {
      const int c_ = t & 1, nx = c_ ^ 1;
      if (t < 15) {
        LOAD_A((t + 1) * 32);                      // issue next-tile loads first
        STAGE_B((t + 1) * 32, nx);
      }
      bf16x8 af[2], bf[4];
      #pragma unroll
      for (int mi = 0; mi < 2; ++mi)
        af[mi] = *(const bf16x8*)&As[c_][(wm + mi * 16 + rl) * 32 + kl];
      #pragma unroll
      for (int ni = 0; ni < 4; ++ni)
        bf[ni] = *(const bf16x8*)&Bs[c_][(wn + ni * 16 + rl) * 32 + kl];
      #pragma unroll
      for (int mi = 0; mi < 2; ++mi)
        #pragma unroll
        for (int ni = 0; ni < 4; ++ni)
          acc[mi][ni] = __builtin_amdgcn_mfma_f32_16x16x32_bf16(af[mi], bf[ni], acc[mi][ni], 0, 0, 0);
      if (t < 15) WRITE_A(nx);                     // convert+ds_write after MFMA
      __syncthreads();
    }

    const int rq = (lane >> 4) * 4;                // D: col=lane&15, row=rq+j
    #pragma unroll
    for (int mi = 0; mi < 2; ++mi)
      #pragma unroll
      for (int ni = 0; ni < 4; ++ni) {
        const int col = bn + wn + ni * 16 + rl;
        #pragma unroll
        for (int j = 0; j < 4; ++j) {
          const int row = bm + wm + mi * 16 + rq + j;
          H[(size_t)row * DF + col] = __float2bfloat16(acc[mi][ni][j]);
        }
      }
    #undef LOAD_A
    #undef STAGE_B
    #undef WRITE_A
  } else {
    // ---- adjacency scan path: same-register reload pipeline ----
    const int rbase = (id - 1024) * 16 + wv * 4;   // 4 rows per wave
    float4 cur[8];
    {
      const float4* r4 = (const float4*)(adj + (size_t)rbase * NCOLS);
      #pragma unroll
      for (int k = 0; k < 8; ++k) cur[k] = r4[k * 64 + lane];
    }
    #pragma unroll
    for (int g = 0; g < 4; ++g) {
      const int r = rbase + g;
      const int n = r & (NCOLS - 1);
      unsigned m = 0;                              // consume cur -> mask
      #pragma unroll
      for (int k = 0; k < 8; ++k) {
        m |= (cur[k].x != 0.0f ? 1u : 0u) << (4 * k);
        m |= (cur[k].y != 0.0f ? 1u : 0u) << (4 * k + 1);
        m |= (cur[k].z != 0.0f ? 1u : 0u) << (4 * k + 2);
        m |= (cur[k].w != 0.0f ? 1u : 0u) << (4 * k + 3);
      }
      if (g < 3) {                                 // reload same regs; overlaps
        const float4* rn = (const float4*)(adj + (size_t)(r + 1) * NCOLS);
        #pragma unroll
        for (int k = 0; k < 8; ++k) cur[k] = rn[k * 64 + lane];
      }
      if (lane == ((n >> 2) & 63))                 // force self-loop bit
        m |= 1u << (((n >> 8) << 2) | (n & 3));
      const int c_ = __popc(m);
      int inc = c_;                                // inclusive wave prefix-scan
      #pragma unroll
      for (int off = 1; off < 64; off <<= 1) {
        const int tv = __shfl_up(inc, off);
        if (lane >= off) inc += tv;
      }
      const int tot = __shfl(inc, 63);
      int p = inc - c_;                            // exclusive prefix
      unsigned mm = m;
      const size_t eb = (size_t)r * CAP;
      while (mm) {                                 // <= ~3 iters per lane
        const int bpos = __ffs(mm) - 1;
        mm &= mm - 1;
        if (p < CAP)
          edges[eb + p] = ((bpos >> 2) << 8) + (lane << 2) + (bpos & 3);
        ++p;
      }
      if (lane == 63) {
        cnt[r] = tot < CAP ? tot : CAP;
        dinv[r] = rsqrtf((float)tot);              // deg >= 1 (self-loop)
      }
    }
  }
}

// ---------------------------------------------------------------------------
// fast tanh: 1 - 2/(e^{2x}+1). v_exp + fast-div; saturates correctly at +-inf.
// ---------------------------------------------------------------------------
__device__ __forceinline__ float fast_tanh(float x) {
  const float t = __expf(2.0f * x);
  return 1.0f - __fdividef(2.0f, t + 1.0f);
}

// ---------------------------------------------------------------------------
// K2: aggregate (R12/R9 form, best measured). 4096 blocks x 4 waves =
// 1 row/wave. batch = blk&7 -> XCD pin. 8 broadcast index loads + weights +
// 8 independent gathers in flight per chunk.
// ---------------------------------------------------------------------------
__global__ __launch_bounds__(256) void aggregate(
    const __hip_bfloat16* __restrict__ h, const int* __restrict__ cnt,
    const int* __restrict__ edges, const float* __restrict__ dinv,
    const float* __restrict__ bias, float* __restrict__ out) {
  const int lane = threadIdx.x & 63;
  const int wv = threadIdx.x >> 6;
  const int batch = blockIdx.x & 7;                // -> XCD pin
  const int qb = blockIdx.x >> 3;                  // 0..511
  const int rn = qb * 4 + wv;                      // row within batch
  const int r = (batch << 11) + rn;
  const int c = cnt[r];
  const float* dv = dinv + (batch << 11);
  const uint4* hbase = (const uint4*)(h + (size_t)(batch << 11) * DF);
  const int* eb = edges + (size_t)r * CAP;

  float acc[8] = {0.f,0.f,0.f,0.f,0.f,0.f,0.f,0.f};
  for (int e = 0; e < c; e += 8) {                 // wave-uniform chunks
    int   mj[8];
    float wj[8];
    uint4 vj[8];
    #pragma unroll
    for (int j = 0; j < 8; ++j)                    // 8 broadcast index loads
      if (e + j < c) mj[j] = eb[e + j];
    #pragma unroll
    for (int j = 0; j < 8; ++j)                    // weights + gathers in flight
      if (e + j < c) {
        wj[j] = dv[mj[j]];
        vj[j] = hbase[(size_t)mj[j] * 64 + lane];
      }
    #pragma unroll
    for (int j = 0; j < 8; ++j)
      if (e + j < c) {
        const float wt = wj[j];
        acc[0] += wt * __uint_as_float(vj[j].x << 16);
        acc[1] += wt * __uint_as_float(vj[j].x & 0xffff0000u);
        acc[2] += wt * __uint_as_float(vj[j].y << 16);
        acc[3] += wt * __uint_as_float(vj[j].y & 0xffff0000u);
        acc[4] += wt * __uint_as_float(vj[j].z << 16);
        acc[5] += wt * __uint_as_float(vj[j].z & 0xffff0000u);
        acc[6] += wt * __uint_as_float(vj[j].w << 16);
        acc[7] += wt * __uint_as_float(vj[j].w & 0xffff0000u);
      }
  }
  const float4* b4 = (const float4*)bias;
  const float4 bb0 = b4[lane * 2];
  const float4 bb1 = b4[lane * 2 + 1];
  const float dn = dv[rn];
  float4 o;
  float* op = out + (size_t)r * DF + lane * 8;
  o.x = fast_tanh(acc[0] * dn + bb0.x);
  o.y = fast_tanh(acc[1] * dn + bb0.y);
  o.z = fast_tanh(acc[2] * dn + bb0.z);
  o.w = fast_tanh(acc[3] * dn + bb0.w);
  *(float4*)op = o;
  o.x = fast_tanh(acc[4] * dn + bb1.x);
  o.y = fast_tanh(acc[5] * dn + bb1.y);
  o.z = fast_tanh(acc[6] * dn + bb1.z);
  o.w = fast_tanh(acc[7] * dn + bb1.w);
  *(float4*)(op + 4) = o;
}

// ---------------------------------------------------------------------------
extern "C" void kernel_launch(void* const* d_in, const int* in_sizes, int n_in,
                              void* d_out, int out_size, void* d_ws, size_t ws_size,
                              hipStream_t stream) {
  const float* X    = (const float*)d_in[0];   // [8,2048,512]
  const float* adj  = (const float*)d_in[1];   // [8,2048,2048]
  const float* W    = (const float*)d_in[2];   // [512,512]
  const float* bias = (const float*)d_in[3];   // [512]
  float* out = (float*)d_out;

  char* ws = (char*)d_ws;
  __hip_bfloat16* h    = (__hip_bfloat16*)(ws);                    // 16,777,216 B
  __hip_bfloat16* WT   = (__hip_bfloat16*)(ws + 16777216);         //    524,288 B
  float*          dinv = (float*)(ws + 17301504);                  //     65,536 B
  int*            cnt  = (int*)  (ws + 17367040);                  //     65,536 B
  int*            edges= (int*)  (ws + 17432576);                  //  4,194,304 B
  // total ws: 21,626,880 B

  wt_kernel<<<64, 256, 0, stream>>>(W, WT);
  fused_k<<<2048, 256, 0, stream>>>(X, WT, adj, h, cnt, edges, dinv);
  aggregate<<<4096, 256, 0, stream>>>(h, cnt, edges, dinv, bias, out);
}

// Round 16
// 70.298 us; speedup vs baseline: 1.0396x; 1.0277x over previous
//
#include <hip/hip_runtime.h>
#include <hip/hip_bf16.h>
#include <math.h>

// Problem: B=8, N=2048, DIN=DOUT=512, adj binary p=0.01
// out = tanh( D^-1/2 (A v I) D^-1/2 (X W) + b )
//
// FINAL (R12 structure — best measured, 70.4us):
//   K1 scan_wt   : blk[0,64)=W->WT bf16; blk[64,1088)=adj scan (nibble masks,
//                  16 rows/blk). 134MB cold adj -> ~22us = HBM floor.
//   K2 gemm_k    : H = X @ W bf16. 64x128 tile, BK=32, 1024 blocks (4+/CU),
//                  dbuf LDS, fp32-A reg-staged, WT via global_load_lds,
//                  panel->XCD pin (aligns h production with agg's batch pin).
//   K3 aggregate : 1 row/wave, 8-edge chunks, wave-uniform broadcast loads,
//                  8 gathers in flight, fast tanh, batch->XCD pin. ~22us =
//                  L2 gather floor (352MB fixed; fp8 shrink fails numerics).
// Refuted: fusion x3 (R3/R11/R14), persistent kernel (R5), fp8 h (R15),
//          block-per-row agg (R13), weight-fold (R10 neutral).

#define NROWS 16384
#define NCOLS 2048
#define DF    512
#define CAP   64        // max edges/row (Binom(2048,0.01): mean ~21.5, P(>=64)~0)

typedef __attribute__((ext_vector_type(8))) short bf16x8;
typedef __attribute__((ext_vector_type(4))) float f32x4;
typedef const void __attribute__((address_space(1))) gvoid_t;
typedef void __attribute__((address_space(3))) svoid_t;

// ---------------------------------------------------------------------------
// K1: blocks [0,64) W->WT bf16; blocks [64,1088) adjacency scan, 16 rows each.
// ---------------------------------------------------------------------------
__global__ __launch_bounds__(256) void scan_wt(
    const float* __restrict__ W, __hip_bfloat16* __restrict__ WT,
    const float* __restrict__ adj, int* __restrict__ cnt,
    int* __restrict__ edges, float* __restrict__ dinv) {
  __shared__ float t[64][65];
  const int blk = blockIdx.x;
  const int tid = threadIdx.x;
  if (blk < 64) {                                  // W -> W^T bf16
    const int bx = blk & 7, by = blk >> 3;
    const int tx = tid & 63, ty = tid >> 6;
    #pragma unroll
    for (int i = 0; i < 16; ++i)
      t[ty + i * 4][tx] = W[(size_t)(by * 64 + ty + i * 4) * DF + bx * 64 + tx];
    __syncthreads();
    #pragma unroll
    for (int i = 0; i < 16; ++i)                   // WT[n][k] = W[k][n]
      WT[(size_t)(bx * 64 + ty + i * 4) * DF + by * 64 + tx] =
          __float2bfloat16(t[tx][ty + i * 4]);
    return;
  }
  // adjacency scan: 16 rows per block, 4 rows per wave, 2-deep pipeline
  const int lane = tid & 63;
  const int wv = tid >> 6;
  const int rbase = (blk - 64) * 16 + wv * 4;
  float4 cur[8], nxt[8];
  {
    const float4* r4 = (const float4*)(adj + (size_t)rbase * NCOLS);
    #pragma unroll
    for (int k = 0; k < 8; ++k) cur[k] = r4[k * 64 + lane];
  }
  #pragma unroll
  for (int g = 0; g < 4; ++g) {
    const int r = rbase + g;
    if (g < 3) {
      const float4* rn = (const float4*)(adj + (size_t)(r + 1) * NCOLS);
      #pragma unroll
      for (int k = 0; k < 8; ++k) nxt[k] = rn[k * 64 + lane];
    }
    const int n = r & (NCOLS - 1);
    unsigned m = 0;
    #pragma unroll
    for (int k = 0; k < 8; ++k) {
      m |= (cur[k].x != 0.0f ? 1u : 0u) << (4 * k);
      m |= (cur[k].y != 0.0f ? 1u : 0u) << (4 * k + 1);
      m |= (cur[k].z != 0.0f ? 1u : 0u) << (4 * k + 2);
      m |= (cur[k].w != 0.0f ? 1u : 0u) << (4 * k + 3);
    }
    if (lane == ((n >> 2) & 63))                   // force self-loop bit
      m |= 1u << (((n >> 8) << 2) | (n & 3));
    const int c_ = __popc(m);
    int inc = c_;                                  // inclusive wave prefix-scan
    #pragma unroll
    for (int off = 1; off < 64; off <<= 1) {
      const int tv = __shfl_up(inc, off);
      if (lane >= off) inc += tv;
    }
    const int tot = __shfl(inc, 63);
    int p = inc - c_;                              // exclusive prefix
    unsigned mm = m;
    const size_t eb = (size_t)r * CAP;
    while (mm) {                                   // <= ~3 iters per lane
      const int bpos = __ffs(mm) - 1;
      mm &= mm - 1;
      if (p < CAP)
        edges[eb + p] = ((bpos >> 2) << 8) + (lane << 2) + (bpos & 3);
      ++p;
    }
    if (lane == 63) {
      cnt[r] = tot < CAP ? tot : CAP;
      dinv[r] = rsqrtf((float)tot);                // deg >= 1 (self-loop)
    }
    #pragma unroll
    for (int k = 0; k < 8; ++k) cur[k] = nxt[k];
  }
}

// ---------------------------------------------------------------------------
// K2: H = X @ WT^T. 64x128 tile, BK=32, 1024 blocks (4+ blocks/CU),
//     4 waves (2x2: 32x64 each), double-buffered LDS (24KB total).
//     A: fp32 reg-staged -> bf16 -> ds_write. B: WT bf16 via global_load_lds.
// ---------------------------------------------------------------------------
__global__ __launch_bounds__(256) void gemm_k(
    const float* __restrict__ X, const __hip_bfloat16* __restrict__ WT,
    __hip_bfloat16* __restrict__ H) {
  __shared__ __hip_bfloat16 As[2][64 * 32];        // 2 x 4 KB  [row][k]
  __shared__ __hip_bfloat16 Bs[2][128 * 32];       // 2 x 8 KB  [n][k]
  const int tid = threadIdx.x;
  const int lane = tid & 63;
  const int w = tid >> 6;
  const int id = blockIdx.x;
  const int xcd = id & 7;
  const int q = id >> 3;                           // 0..127
  const int bm = (xcd * 32 + (q >> 2)) * 64;       // panel -> XCD pin
  const int bn = (q & 3) * 128;

  const int wm = (w >> 1) * 32;                    // wave tile 32x64
  const int wn = (w & 1) * 64;
  const int srow = tid >> 2;                       // staging row (0..63)
  const int scol = (tid & 3) * 8;                  // 8 elems = 16B
  const int kl = (lane >> 4) * 8;
  const int rl = lane & 15;

  f32x4 acc[2][4] = {};
  float4 ar0, ar1;                                 // A prefetch regs (8 floats)

  #define LOAD_A(k0)  do {                                              \
    const float4* g_ = (const float4*)(X + (size_t)(bm + srow) * DF + (k0) + scol); \
    ar0 = g_[0]; ar1 = g_[1]; } while (0)

  #define STAGE_B(k0, buf)  do {                                        \
    _Pragma("unroll")                                                   \
    for (int i = 0; i < 2; ++i) {                                       \
      const __hip_bfloat16* gb = WT + (size_t)(bn + i * 64 + srow) * DF + (k0) + scol; \
      char* lb = (char*)&Bs[buf][0] + i * 4096 + w * 1024;              \
      __builtin_amdgcn_global_load_lds((gvoid_t*)gb, (svoid_t*)lb, 16, 0, 0); \
    } } while (0)

  #define WRITE_A(buf)  do {                                            \
    float xs[8];                                                        \
    *(float4*)&xs[0] = ar0; *(float4*)&xs[4] = ar1;                     \
    union { __hip_bfloat16 hh[8]; uint4 q_; } pk;                       \
    _Pragma("unroll")                                                   \
    for (int i = 0; i < 8; ++i) pk.hh[i] = __float2bfloat16(xs[i]);     \
    char* la = (char*)&As[buf][0] + srow * 64 + scol * 2;               \
    *(uint4*)la = pk.q_; } while (0)

  LOAD_A(0);
  STAGE_B(0, 0);
  WRITE_A(0);
  __syncthreads();

  for (int t = 0; t < 16; ++t) {
    const int c_ = t & 1, nx = c_ ^ 1;
    if (t < 15) {
      LOAD_A((t + 1) * 32);                        // issue next-tile loads first
      STAGE_B((t + 1) * 32, nx);
    }
    bf16x8 af[2], bf[4];
    #pragma unroll
    for (int mi = 0; mi < 2; ++mi)
      af[mi] = *(const bf16x8*)&As[c_][(wm + mi * 16 + rl) * 32 + kl];
    #pragma unroll
    for (int ni = 0; ni < 4; ++ni)
      bf[ni] = *(const bf16x8*)&Bs[c_][(wn + ni * 16 + rl) * 32 + kl];
    #pragma unroll
    for (int mi = 0; mi < 2; ++mi)
      #pragma unroll
      for (int ni = 0; ni < 4; ++ni)
        acc[mi][ni] = __builtin_amdgcn_mfma_f32_16x16x32_bf16(af[mi], bf[ni], acc[mi][ni], 0, 0, 0);
    if (t < 15) WRITE_A(nx);                       // convert+ds_write after MFMA
    __syncthreads();
  }

  const int rq = (lane >> 4) * 4;                  // D: col=lane&15, row=rq+j
  #pragma unroll
  for (int mi = 0; mi < 2; ++mi)
    #pragma unroll
    for (int ni = 0; ni < 4; ++ni) {
      const int col = bn + wn + ni * 16 + rl;
      #pragma unroll
      for (int j = 0; j < 4; ++j) {
        const int row = bm + wm + mi * 16 + rq + j;
        H[(size_t)row * DF + col] = __float2bfloat16(acc[mi][ni][j]);
      }
    }
  #undef LOAD_A
  #undef STAGE_B
  #undef WRITE_A
}

// ---------------------------------------------------------------------------
// fast tanh: 1 - 2/(e^{2x}+1). v_exp + fast-div; saturates correctly at +-inf.
// ---------------------------------------------------------------------------
__device__ __forceinline__ float fast_tanh(float x) {
  const float t = __expf(2.0f * x);
  return 1.0f - __fdividef(2.0f, t + 1.0f);
}

// ---------------------------------------------------------------------------
// K3: aggregate. 4096 blocks x 4 waves = 1 row/wave; batch = blk&7 -> XCD pin.
// 8 wave-uniform broadcast index loads + weights + 8 independent uint4
// gathers in flight per chunk; fast tanh epilogue.
// ---------------------------------------------------------------------------
__global__ __launch_bounds__(256) void aggregate(
    const __hip_bfloat16* __restrict__ h, const int* __restrict__ cnt,
    const int* __restrict__ edges, const float* __restrict__ dinv,
    const float* __restrict__ bias, float* __restrict__ out) {
  const int lane = threadIdx.x & 63;
  const int wv = threadIdx.x >> 6;
  const int batch = blockIdx.x & 7;                // -> XCD pin
  const int qb = blockIdx.x >> 3;                  // 0..511
  const int rn = qb * 4 + wv;                      // row within batch
  const int r = (batch << 11) + rn;
  const int c = cnt[r];
  const float* dv = dinv + (batch << 11);
  const uint4* hbase = (const uint4*)(h + (size_t)(batch << 11) * DF);
  const int* eb = edges + (size_t)r * CAP;

  float acc[8] = {0.f,0.f,0.f,0.f,0.f,0.f,0.f,0.f};
  for (int e = 0; e < c; e += 8) {                 // wave-uniform chunks
    int   mj[8];
    float wj[8];
    uint4 vj[8];
    #pragma unroll
    for (int j = 0; j < 8; ++j)                    // 8 broadcast index loads
      if (e + j < c) mj[j] = eb[e + j];
    #pragma unroll
    for (int j = 0; j < 8; ++j)                    // weights + gathers in flight
      if (e + j < c) {
        wj[j] = dv[mj[j]];
        vj[j] = hbase[(size_t)mj[j] * 64 + lane];
      }
    #pragma unroll
    for (int j = 0; j < 8; ++j)
      if (e + j < c) {
        const float wt = wj[j];
        acc[0] += wt * __uint_as_float(vj[j].x << 16);
        acc[1] += wt * __uint_as_float(vj[j].x & 0xffff0000u);
        acc[2] += wt * __uint_as_float(vj[j].y << 16);
        acc[3] += wt * __uint_as_float(vj[j].y & 0xffff0000u);
        acc[4] += wt * __uint_as_float(vj[j].z << 16);
        acc[5] += wt * __uint_as_float(vj[j].z & 0xffff0000u);
        acc[6] += wt * __uint_as_float(vj[j].w << 16);
        acc[7] += wt * __uint_as_float(vj[j].w & 0xffff0000u);
      }
  }
  const float4* b4 = (const float4*)bias;
  const float4 bb0 = b4[lane * 2];
  const float4 bb1 = b4[lane * 2 + 1];
  const float dn = dv[rn];
  float4 o;
  float* op = out + (size_t)r * DF + lane * 8;
  o.x = fast_tanh(acc[0] * dn + bb0.x);
  o.y = fast_tanh(acc[1] * dn + bb0.y);
  o.z = fast_tanh(acc[2] * dn + bb0.z);
  o.w = fast_tanh(acc[3] * dn + bb0.w);
  *(float4*)op = o;
  o.x = fast_tanh(acc[4] * dn + bb1.x);
  o.y = fast_tanh(acc[5] * dn + bb1.y);
  o.z = fast_tanh(acc[6] * dn + bb1.z);
  o.w = fast_tanh(acc[7] * dn + bb1.w);
  *(float4*)(op + 4) = o;
}

// ---------------------------------------------------------------------------
extern "C" void kernel_launch(void* const* d_in, const int* in_sizes, int n_in,
                              void* d_out, int out_size, void* d_ws, size_t ws_size,
                              hipStream_t stream) {
  const float* X    = (const float*)d_in[0];   // [8,2048,512]
  const float* adj  = (const float*)d_in[1];   // [8,2048,2048]
  const float* W    = (const float*)d_in[2];   // [512,512]
  const float* bias = (const float*)d_in[3];   // [512]
  float* out = (float*)d_out;

  char* ws = (char*)d_ws;
  __hip_bfloat16* h    = (__hip_bfloat16*)(ws);                    // 16,777,216 B
  __hip_bfloat16* WT   = (__hip_bfloat16*)(ws + 16777216);         //    524,288 B
  float*          dinv = (float*)(ws + 17301504);                  //     65,536 B
  int*            cnt  = (int*)  (ws + 17367040);                  //     65,536 B
  int*            edges= (int*)  (ws + 17432576);                  //  4,194,304 B
  // total ws: 21,626,880 B

  scan_wt<<<1088, 256, 0, stream>>>(W, WT, adj, cnt, edges, dinv);
  gemm_k<<<1024, 256, 0, stream>>>(X, WT, h);
  aggregate<<<4096, 256, 0, stream>>>(h, cnt, edges, dinv, bias, out);
}